// Round 10
// baseline (264.684 us; speedup 1.0000x reference)
//
#include <hip/hip_runtime.h>
#include <hip/hip_bf16.h>
#include <math.h>

// Problem constants (reference: D=300, TOPK=20, setup N=2,T=4096,h=6)
#define T      4096
#define Dm     300
#define NH     6
#define DH     50
#define NB     2
#define NBATCH 12   // NH*NB
#define KTOP   20
#define NCAND  48   // rank20->48 margin ~0.28 >> bf16 score err ~6e-3
#define QC     4    // score kernel q-chunks (grid.z), 1024 queries each
#define RQC2   64   // rescore q-chunks (64 queries each, one per lane)
#define NBINS  4096 // radix-select histogram bins (top 12 key bits)
#define BMAX   1024 // boundary-bin list cap
#define WCH    30720        // W frag chunks: 2z*12jt*2nt*10ks*64lane
#define INITN  (NBATCH * T + NBATCH * NCAND + NBATCH)   // pamax1+rmax1+done_ct

typedef short  bs8  __attribute__((ext_vector_type(8)));   // 8 bf16 = 4 VGPRs
typedef float  f4   __attribute__((ext_vector_type(4)));

static __device__ __forceinline__ unsigned short f2bf(float f) {
    union { float f; unsigned u; } x{f};
    unsigned r = x.u + 0x7fffu + ((x.u >> 16) & 1u);   // RNE
    return (unsigned short)(r >> 16);
}
static __device__ __forceinline__ float bf2f(unsigned short h) {
    union { unsigned u; float f; } x;
    x.u = ((unsigned)h) << 16;
    return x.f;
}
// order-preserving float <-> uint key (a>b <=> fkey(a)>fkey(b))
static __device__ __forceinline__ unsigned fkey(float f) {
    unsigned u = __float_as_uint(f);
    return (u & 0x80000000u) ? ~u : (u | 0x80000000u);
}
static __device__ __forceinline__ float fkey_inv(unsigned u) {
    return (u & 0x80000000u) ? __uint_as_float(u & 0x7fffffffu)
                             : __uint_as_float(~u);
}

// ---------------------------------------------------------------------------
// Kernel 0: W -> bf16 hi/lo frag-major  +  zero-init pamax1/rmax1/done_ct.
// ---------------------------------------------------------------------------
__global__ __launch_bounds__(256) void wfrag_kernel(
    const float* __restrict__ Wq, const float* __restrict__ Wk,
    unsigned short* __restrict__ Whf, unsigned short* __restrict__ Wlf,
    unsigned* __restrict__ initp)
{
    for (unsigned g = blockIdx.x * 256 + threadIdx.x; g < INITN; g += gridDim.x * 256)
        initp[g] = 0u;

    const int idx = blockIdx.x * 256 + threadIdx.x;
    if (idx >= WCH) return;
    const int lane = idx & 63, rest = idx >> 6;
    const int ks = rest % 10, r2 = rest / 10;
    const int nt = r2 & 1, r3 = r2 >> 1;
    const int jtg = r3 % 12, z = r3 / 12;
    const int n16 = lane & 15, quad = lane >> 4;
    const int j = jtg * 32 + nt * 16 + n16;
    const int head = j >> 6, dd = j & 63;
    const float* W = z ? Wk : Wq;

    bs8 vh, vl;
#pragma unroll
    for (int e = 0; e < 8; ++e) {
        int k = ks * 32 + quad * 8 + e;
        float v = (dd < DH && k < 300) ? W[(head * DH + dd) * 300 + (k < 300 ? k : 0)] : 0.f;
        unsigned short h = f2bf(v);
        vh[e] = (short)h;
        vl[e] = (short)f2bf(v - bf2f(h));
    }
    *(bs8*)(Whf + (size_t)idx * 8) = vh;
    *(bs8*)(Wlf + (size_t)idx * 8) = vl;
}

// ---------------------------------------------------------------------------
// Kernel 1: projection, split-bf16 MFMA (XhWh + XlWh + XhWl), A read ONCE.
// ---------------------------------------------------------------------------
__global__ __launch_bounds__(256, 1) void proj_mfma_kernel(
    const float* __restrict__ Xq, const float* __restrict__ Xk,
    const unsigned short* __restrict__ Whf, const unsigned short* __restrict__ Wlf,
    float* __restrict__ Qt, float* __restrict__ Kt,
    unsigned short* __restrict__ Qb, unsigned short* __restrict__ Kb)
{
    __shared__ unsigned short Bsh[2][2560 * 8];
    __shared__ unsigned short Tr[4][32][40];

    const int z  = blockIdx.z;
    const int jg = blockIdx.y;
    const int m0 = blockIdx.x * 128;
    const float* X = z ? Xk : Xq;
    float*          Ytf = z ? Kt : Qt;
    unsigned short* Ytb = z ? Kb : Qb;

    const int tid = threadIdx.x;
    const int wave = tid >> 6, lane = tid & 63;
    const int m16 = lane & 15, quad = lane >> 4;
    const int n = m0 >> 12, t0 = m0 & (T - 1);

    bs8 Ah[2][10], Al[2][10];
#pragma unroll
    for (int mt = 0; mt < 2; ++mt) {
        const float* rowp = X + (size_t)(m0 + wave * 32 + mt * 16 + m16) * 300;
#pragma unroll
        for (int ks = 0; ks < 10; ++ks) {
            float f[8];
            if (ks < 9) {
                float4 a = *(const float4*)(rowp + ks * 32 + quad * 8);
                float4 c = *(const float4*)(rowp + ks * 32 + quad * 8 + 4);
                f[0] = a.x; f[1] = a.y; f[2] = a.z; f[3] = a.w;
                f[4] = c.x; f[5] = c.y; f[6] = c.z; f[7] = c.w;
            } else {
#pragma unroll
                for (int e = 0; e < 8; ++e) {
                    int k = 288 + quad * 8 + e;
                    f[e] = (k < 300) ? rowp[k < 300 ? k : 0] : 0.f;
                }
            }
#pragma unroll
            for (int e = 0; e < 8; ++e) {
                unsigned short h = f2bf(f[e]);
                Ah[mt][ks][e] = (short)h;
                Al[mt][ks][e] = (short)f2bf(f[e] - bf2f(h));
            }
        }
    }

    bs8 rh[5], rl[5];
    {
        size_t cb = (size_t)(z * 12 + jg * 6) * 1280;
#pragma unroll
        for (int i = 0; i < 5; ++i) {
            int c = i * 256 + tid;
            rh[i] = *(const bs8*)(Whf + (cb + c) * 8);
            rl[i] = *(const bs8*)(Wlf + (cb + c) * 8);
        }
#pragma unroll
        for (int i = 0; i < 5; ++i) {
            int c = i * 256 + tid;
            *(bs8*)&Bsh[0][c * 8]          = rh[i];
            *(bs8*)&Bsh[0][(1280 + c) * 8] = rl[i];
        }
    }

    f4 acc[2][2] = {{{0.f,0.f,0.f,0.f},{0.f,0.f,0.f,0.f}},
                    {{0.f,0.f,0.f,0.f},{0.f,0.f,0.f,0.f}}};

    for (int jt = 0; jt < 6; ++jt) {
        __syncthreads();

        if (jt < 5) {
            size_t cb = (size_t)(z * 12 + jg * 6 + jt + 1) * 1280;
#pragma unroll
            for (int i = 0; i < 5; ++i) {
                int c = i * 256 + tid;
                rh[i] = *(const bs8*)(Whf + (cb + c) * 8);
                rl[i] = *(const bs8*)(Wlf + (cb + c) * 8);
            }
        }

        const unsigned short* Bbuf = Bsh[jt & 1];
#pragma unroll
        for (int ks = 0; ks < 10; ++ks) {
#pragma unroll
            for (int nt = 0; nt < 2; ++nt) {
                bs8 bh = *(const bs8*)&Bbuf[((nt * 10 + ks) * 64 + lane) * 8];
                bs8 bl = *(const bs8*)&Bbuf[((1280 + (nt * 10 + ks) * 64) + lane) * 8];
#pragma unroll
                for (int mt = 0; mt < 2; ++mt) {
                    acc[mt][nt] = __builtin_amdgcn_mfma_f32_16x16x32_bf16(Ah[mt][ks], bh, acc[mt][nt], 0, 0, 0);
                    acc[mt][nt] = __builtin_amdgcn_mfma_f32_16x16x32_bf16(Al[mt][ks], bh, acc[mt][nt], 0, 0, 0);
                    acc[mt][nt] = __builtin_amdgcn_mfma_f32_16x16x32_bf16(Ah[mt][ks], bl, acc[mt][nt], 0, 0, 0);
                }
            }
        }

        const int jtg  = jg * 6 + jt;
        const int head = jtg >> 1, d0 = (jtg & 1) * 32;
        const int b    = head * NB + n;

#pragma unroll
        for (int nt = 0; nt < 2; ++nt) {
            const int dd = d0 + nt * 16 + m16;
            if (dd < DH) {
                float* base = Ytf + ((size_t)b * DH + dd) * T + t0 + wave * 32;
#pragma unroll
                for (int mt = 0; mt < 2; ++mt)
                    *(float4*)(base + mt * 16 + quad * 4) =
                        make_float4(acc[mt][nt][0], acc[mt][nt][1], acc[mt][nt][2], acc[mt][nt][3]);
            }
        }

#pragma unroll
        for (int mt = 0; mt < 2; ++mt)
#pragma unroll
            for (int nt = 0; nt < 2; ++nt)
#pragma unroll
                for (int r = 0; r < 4; ++r)
                    Tr[wave][mt * 16 + quad * 4 + r][nt * 16 + m16] = f2bf(acc[mt][nt][r]);
        {
            const int rr = lane >> 1, p = lane & 1;
            unsigned short* dst = Ytb + ((size_t)b * T + t0 + wave * 32 + rr) * 64 + d0 + p * 16;
            *(bs8*)dst       = *(const bs8*)&Tr[wave][rr][p * 16];
            *(bs8*)(dst + 8) = *(const bs8*)&Tr[wave][rr][p * 16 + 8];
        }

#pragma unroll
        for (int mt = 0; mt < 2; ++mt)
#pragma unroll
            for (int nt = 0; nt < 2; ++nt)
                acc[mt][nt] = (f4){0.f, 0.f, 0.f, 0.f};

        __syncthreads();
        if (jt < 5) {
#pragma unroll
            for (int i = 0; i < 5; ++i) {
                int c = i * 256 + tid;
                *(bs8*)&Bsh[(jt + 1) & 1][c * 8]          = rh[i];
                *(bs8*)&Bsh[(jt + 1) & 1][(1280 + c) * 8] = rl[i];
            }
        }
    }
}

// ---------------------------------------------------------------------------
// Kernel 2: bf16 MFMA scores + column max -> atomicMax(fkey) into pamax1.
// ---------------------------------------------------------------------------
__global__ __launch_bounds__(256) void score_mfma_kernel(
    const unsigned short* __restrict__ Qb, const unsigned short* __restrict__ Kb,
    unsigned* __restrict__ pamax1)
{
    __shared__ unsigned short Qlds[2][1024 * 8];   // 2 x 16 KB, XOR-swizzled

    const int kb   = blockIdx.x;
    const int b    = blockIdx.y;
    const int qc   = blockIdx.z;
    const int tid  = threadIdx.x;
    const int wave = tid >> 6, lane = tid & 63;
    const int m16  = lane & 15, quad = lane >> 4;

    const int k0 = kb * 256 + wave * 64;

    bs8 Bf[4][2];
#pragma unroll
    for (int kt = 0; kt < 4; ++kt)
#pragma unroll
        for (int h = 0; h < 2; ++h)
            Bf[kt][h] = *(const bs8*)(Kb + ((size_t)(b * T + k0 + kt * 16 + m16)) * 64
                                         + quad * 8 + h * 32);

    float cmax[4];
#pragma unroll
    for (int kt = 0; kt < 4; ++kt) cmax[kt] = -INFINITY;

    const int r_ = tid >> 3, c2_ = tid & 7;
    bs8 pre[4];
#pragma unroll
    for (int i = 0; i < 4; ++i)
        pre[i] = *(const bs8*)(Qb + ((size_t)(b * T + qc * 1024 + i * 32 + r_)) * 64 + c2_ * 8);
#pragma unroll
    for (int i = 0; i < 4; ++i) {
        int row = i * 32 + r_;
        *(bs8*)&Qlds[0][(row * 8 + (c2_ ^ (row & 7))) * 8] = pre[i];
    }

    for (int it = 0; it < 8; ++it) {
        __syncthreads();
        if (it < 7) {
            const int q0 = qc * 1024 + (it + 1) * 128;
#pragma unroll
            for (int i = 0; i < 4; ++i)
                pre[i] = *(const bs8*)(Qb + ((size_t)(b * T + q0 + i * 32 + r_)) * 64 + c2_ * 8);
        }

        const unsigned short* Ql = Qlds[it & 1];
#pragma unroll
        for (int mt = 0; mt < 8; ++mt) {
            const int row = mt * 16 + m16;
            bs8 A0 = *(const bs8*)&Ql[(row * 8 + (quad ^ (row & 7))) * 8];
            bs8 A1 = *(const bs8*)&Ql[(row * 8 + ((quad + 4) ^ (row & 7))) * 8];
#pragma unroll
            for (int kt = 0; kt < 4; ++kt) {
                f4 acc = {0.f, 0.f, 0.f, 0.f};
                acc = __builtin_amdgcn_mfma_f32_16x16x32_bf16(A0, Bf[kt][0], acc, 0, 0, 0);
                acc = __builtin_amdgcn_mfma_f32_16x16x32_bf16(A1, Bf[kt][1], acc, 0, 0, 0);
                cmax[kt] = fmaxf(cmax[kt],
                                 fmaxf(fmaxf(acc[0], acc[1]), fmaxf(acc[2], acc[3])));
            }
        }
        __syncthreads();
        if (it < 7) {
#pragma unroll
            for (int i = 0; i < 4; ++i) {
                int row = i * 32 + r_;
                *(bs8*)&Qlds[(it + 1) & 1][(row * 8 + (c2_ ^ (row & 7))) * 8] = pre[i];
            }
        }
    }

#pragma unroll
    for (int kt = 0; kt < 4; ++kt) {
        float v = cmax[kt];
        v = fmaxf(v, __shfl_xor(v, 16));
        v = fmaxf(v, __shfl_xor(v, 32));
        if (lane < 16)
            atomicMax(&pamax1[(size_t)b * T + k0 + kt * 16 + lane], fkey(v));
    }
}

// ---------------------------------------------------------------------------
// Kernel 3: per batch (12 blocks), radix-select top-NCAND candidate SET,
// rank-sorted by index -> cand[b][48]; also gathers candKT[b][50][48]
// (K columns of the candidates) so rescore blocks read coalesced.
// ---------------------------------------------------------------------------
__global__ __launch_bounds__(256) void cand_kernel(
    const unsigned* __restrict__ pamax1, const float* __restrict__ Kt,
    int* __restrict__ cand, float* __restrict__ candKT)
{
    __shared__ unsigned vals[T];
    __shared__ int      hist[NBINS];
    __shared__ int      part[256];
    __shared__ int      bidx[BMAX];
    __shared__ unsigned bval[BMAX];
    __shared__ int      candtmp[NCAND];
    __shared__ int      cand_sorted[NCAND];
    __shared__ int      sh_B, sh_nout, sh_nb;

    const int b = blockIdx.x, tid = threadIdx.x;

    for (int i = tid; i < NBINS; i += 256) hist[i] = 0;
    if (tid == 0) { sh_nout = 0; sh_nb = 0; }
    __syncthreads();

    for (int i = tid; i < T; i += 256) {
        unsigned k = pamax1[(size_t)b * T + i];
        vals[i] = k;
        atomicAdd(&hist[k >> 20], 1);
    }
    __syncthreads();
    {
        int s = 0;
#pragma unroll
        for (int k = 0; k < 16; ++k) s += hist[tid * 16 + k];
        part[tid] = s;
        __syncthreads();
        for (int off = 1; off < 256; off <<= 1) {
            int v = (tid + off < 256) ? part[tid + off] : 0;
            __syncthreads();
            part[tid] += v;
            __syncthreads();
        }
        int run = (tid < 255) ? part[tid + 1] : 0;
        for (int k = 15; k >= 0; --k) {
            int bin = tid * 16 + k;
            int c = hist[bin];
            if (run < NCAND && run + c >= NCAND) sh_B = bin;
            run += c;
        }
    }
    __syncthreads();
    const int B = sh_B;

    for (int i = tid; i < T; i += 256) {
        int kb2 = (int)(vals[i] >> 20);
        if (kb2 > B) {
            int p = atomicAdd(&sh_nout, 1);
            candtmp[p] = i;
        } else if (kb2 == B) {
            int p = atomicAdd(&sh_nb, 1);
            if (p < BMAX) { bidx[p] = i; bval[p] = vals[i]; }
        }
    }
    __syncthreads();
    const int c1 = sh_nout, need = NCAND - c1;
    const int nb = (sh_nb < BMAX) ? sh_nb : BMAX;
    if (tid < 64) {
        for (int l = 0; l < need; ++l) {
            unsigned mv = 0; int mp = -1, mt = 0x7fffffff;
            for (int j = tid; j < nb; j += 64) {
                unsigned v = bval[j]; int t = bidx[j];
                if (v > mv || (v == mv && t < mt)) { mv = v; mp = j; mt = t; }
            }
#pragma unroll
            for (int off = 32; off > 0; off >>= 1) {
                unsigned v2 = (unsigned)__shfl_xor((int)mv, off);
                int p2 = __shfl_xor(mp, off);
                int t2 = __shfl_xor(mt, off);
                if (v2 > mv || (v2 == mv && t2 < mt)) { mv = v2; mp = p2; mt = t2; }
            }
            if (tid == 0) candtmp[c1 + l] = (mp >= 0) ? bidx[mp] : 0;
            if (mp >= 0 && tid == (mp & 63)) bval[mp] = 0;
        }
    }
    __syncthreads();

    // rank-sort by index -> deterministic j-order
    if (tid < NCAND) {
        int myt = candtmp[tid], rank = 0;
        for (int j = 0; j < NCAND; ++j) rank += (candtmp[j] < myt);
        cand_sorted[rank] = myt;
    }
    __syncthreads();
    if (tid < NCAND) cand[b * NCAND + tid] = cand_sorted[tid];

    // gather candidate K columns: candKT[b][d][j]
    for (int i = tid; i < DH * NCAND; i += 256) {
        int d = i / NCAND, j = i - d * NCAND;
        candKT[(size_t)b * (DH * NCAND) + i] =
            Kt[((size_t)b * DH + d) * T + cand_sorted[j]];
    }
}

// ---------------------------------------------------------------------------
// Kernel 4: fused rescore + finale. grid (12 b, 64 qch of 64 queries).
// All 4 waves share the block's 64 queries (q = lane); wave w owns candidates
// [w*12, w*12+12). KcT reads are wave-broadcast float4 (conflict-free).
// lane0 atomicMax(fkey) per j into rmax1; last block per b does the exact
// top-20/softmax/gather finale.
// ---------------------------------------------------------------------------
__global__ __launch_bounds__(256) void rescore_final_kernel(
    const int* __restrict__ cand, const float* __restrict__ candKT,
    const float* __restrict__ Qt, const float* __restrict__ Kt,
    unsigned* __restrict__ rmax1, unsigned* __restrict__ done_ct,
    float* __restrict__ out)
{
    __shared__ float KcT[DH][NCAND];   // [50][48], row = 192 B (16B-aligned)
    __shared__ int   cand_s[NCAND];
    __shared__ int   sh_pos;
    __shared__ float selval[KTOP];
    __shared__ int   selidx[KTOP];
    __shared__ float probs[KTOP];

    const int b = blockIdx.x, qch = blockIdx.y;
    const int tid = threadIdx.x, lane = tid & 63, wv = tid >> 6;

    if (tid < NCAND) cand_s[tid] = cand[b * NCAND + tid];
    // coalesced float4 load of the pre-gathered candidate K columns
    for (int i = tid; i < DH * NCAND / 4; i += 256)
        ((float4*)&KcT[0][0])[i] = ((const float4*)(candKT + (size_t)b * (DH * NCAND)))[i];
    __syncthreads();

    const int q = qch * 64 + lane;
    float qv[DH];
#pragma unroll
    for (int d = 0; d < DH; ++d)
        qv[d] = Qt[((size_t)b * DH + d) * T + q];

    const int j0 = wv * 12;
    float cm[12];
#pragma unroll
    for (int j = 0; j < 12; ++j) cm[j] = 0.f;
#pragma unroll
    for (int d = 0; d < DH; ++d) {
        float4 k0 = *(const float4*)&KcT[d][j0];       // wave-broadcast reads
        float4 k1 = *(const float4*)&KcT[d][j0 + 4];
        float4 k2 = *(const float4*)&KcT[d][j0 + 8];
        float x = qv[d];
        cm[0]  = fmaf(x, k0.x, cm[0]);
        cm[1]  = fmaf(x, k0.y, cm[1]);
        cm[2]  = fmaf(x, k0.z, cm[2]);
        cm[3]  = fmaf(x, k0.w, cm[3]);
        cm[4]  = fmaf(x, k1.x, cm[4]);
        cm[5]  = fmaf(x, k1.y, cm[5]);
        cm[6]  = fmaf(x, k1.z, cm[6]);
        cm[7]  = fmaf(x, k1.w, cm[7]);
        cm[8]  = fmaf(x, k2.x, cm[8]);
        cm[9]  = fmaf(x, k2.y, cm[9]);
        cm[10] = fmaf(x, k2.z, cm[10]);
        cm[11] = fmaf(x, k2.w, cm[11]);
    }
#pragma unroll
    for (int j = 0; j < 12; ++j) {
        float v = cm[j];
#pragma unroll
        for (int off = 32; off > 0; off >>= 1)
            v = fmaxf(v, __shfl_xor(v, off));
        if (lane == 0)
            atomicMax(&rmax1[b * NCAND + j0 + j], fkey(v));
    }
    __syncthreads();   // all waves' atomics issued & drained (vmcnt before barrier)
    if (tid == 0) {
        __threadfence();
        sh_pos = atomicAdd(&done_ct[b], 1u);
    }
    __syncthreads();
    if (sh_pos != RQC2 - 1) return;   // uniform per block

    // --- last block for this b: exact finale ---
    if (tid < 64) {
        float v = -INFINITY; int idx = 0x7fffffff;
        if (lane < NCAND) {
            unsigned u = atomicMax(&rmax1[b * NCAND + lane], 0u);  // coherent read
            v = fkey_inv(u) * 0.14142135623730951f;                // 1/sqrt(50)
            idx = cand_s[lane];
        }
        for (int l = 0; l < KTOP; ++l) {
            float mv = v; int mi = idx;
#pragma unroll
            for (int off = 32; off > 0; off >>= 1) {
                float v2 = __shfl_xor(mv, off);
                int   i2 = __shfl_xor(mi, off);
                if (v2 > mv || (v2 == mv && i2 < mi)) { mv = v2; mi = i2; }
            }
            if (idx == mi) v = -INFINITY;   // cand indices distinct
            if (lane == 0) { selval[l] = mv; selidx[l] = mi; }
        }
    }
    __syncthreads();
    if (tid == 0) {
        float m = selval[0];
        float s = 0.f;
        for (int l = 0; l < KTOP; ++l) { float e = expf(selval[l] - m); probs[l] = e; s += e; }
        float inv = 1.f / s;
        for (int l = 0; l < KTOP; ++l) probs[l] *= inv;
    }
    __syncthreads();
    if (tid < DH) {
        float acc = 0.f;
#pragma unroll
        for (int l = 0; l < KTOP; ++l)
            acc += probs[l] * Kt[((size_t)b * DH + tid) * T + selidx[l]];
        int head = b / NB, n = b % NB;
        out[n * Dm + head * DH + tid] = acc;
    }
}

// ---------------------------------------------------------------------------
extern "C" void kernel_launch(void* const* d_in, const int* in_sizes, int n_in,
                              void* d_out, int out_size, void* d_ws, size_t ws_size,
                              hipStream_t stream) {
    const float* querys = (const float*)d_in[0];
    const float* keys   = (const float*)d_in[1];
    const float* Wq     = (const float*)d_in[3];
    const float* Wk     = (const float*)d_in[4];

    float* out = (float*)d_out;
    float* ws  = (float*)d_ws;

    float* Qt = ws;                                       // 12*50*4096 f
    float* Kt = Qt + (size_t)NBATCH * DH * T;             // 12*50*4096 f
    unsigned* pamax1  = (unsigned*)(Kt + (size_t)NBATCH * DH * T);  // 12*4096 u
    unsigned* rmax1   = pamax1 + (size_t)NBATCH * T;      // 12*48 u
    unsigned* done_ct = rmax1 + (size_t)NBATCH * NCAND;   // 12 u
    int* cand = (int*)(done_ct + NBATCH);                 // 12*48 i
    float* candKT = (float*)(cand + NBATCH * NCAND);      // 12*50*48 f
    unsigned short* Qb = (unsigned short*)(candKT + (size_t)NBATCH * DH * NCAND + 4);
    Qb = (unsigned short*)(((uintptr_t)Qb + 15) & ~(uintptr_t)15);
    unsigned short* Kb  = Qb  + (size_t)NBATCH * T * 64;  // 12*4096*64 ush
    unsigned short* Whf = Kb  + (size_t)NBATCH * T * 64;  // WCH*8 ush
    unsigned short* Wlf = Whf + (size_t)WCH * 8;
    // total ~33.6 MB

    wfrag_kernel      <<<(WCH + 255) / 256, 256, 0, stream>>>(Wq, Wk, Whf, Wlf, pamax1);
    proj_mfma_kernel  <<<dim3(64, 2, 2), 256, 0, stream>>>(querys, keys, Whf, Wlf, Qt, Kt, Qb, Kb);
    score_mfma_kernel <<<dim3(16, NBATCH, QC), 256, 0, stream>>>(Qb, Kb, pamax1);
    cand_kernel       <<<NBATCH, 256, 0, stream>>>(pamax1, Kt, cand, candKT);
    rescore_final_kernel<<<dim3(NBATCH, RQC2), 256, 0, stream>>>(cand, candKT, Qt, Kt, rmax1, done_ct, out);
}

// Round 11
// 213.646 us; speedup vs baseline: 1.2389x; 1.2389x over previous
//
#include <hip/hip_runtime.h>
#include <hip/hip_bf16.h>
#include <math.h>

// Problem constants (reference: D=300, TOPK=20, setup N=2,T=4096,h=6)
#define T      4096
#define Dm     300
#define NH     6
#define DH     50
#define NB     2
#define NBATCH 12   // NH*NB
#define KTOP   20
#define NCAND  48   // rank20->48 margin ~0.28 >> bf16 score err ~6e-3
#define QC     4    // score kernel q-chunks (grid.z), 1024 queries each
#define RQC2   64   // rescore q-chunks (64 queries each, one per lane)
#define NBINS  4096 // radix-select histogram bins (top 12 key bits)
#define BMAX   1024 // boundary-bin list cap
#define WCH    30720        // W frag chunks: 2z*12jt*2nt*10ks*64lane
#define INITN  (NBATCH * T + NBATCH * NCAND + NBATCH)   // pamax1+rmax1+done_ct

typedef short  bs8  __attribute__((ext_vector_type(8)));   // 8 bf16 = 4 VGPRs
typedef float  f4   __attribute__((ext_vector_type(4)));

static __device__ __forceinline__ unsigned short f2bf(float f) {
    union { float f; unsigned u; } x{f};
    unsigned r = x.u + 0x7fffu + ((x.u >> 16) & 1u);   // RNE
    return (unsigned short)(r >> 16);
}
static __device__ __forceinline__ float bf2f(unsigned short h) {
    union { unsigned u; float f; } x;
    x.u = ((unsigned)h) << 16;
    return x.f;
}
// order-preserving float <-> uint key (a>b <=> fkey(a)>fkey(b))
static __device__ __forceinline__ unsigned fkey(float f) {
    unsigned u = __float_as_uint(f);
    return (u & 0x80000000u) ? ~u : (u | 0x80000000u);
}
static __device__ __forceinline__ float fkey_inv(unsigned u) {
    return (u & 0x80000000u) ? __uint_as_float(u & 0x7fffffffu)
                             : __uint_as_float(~u);
}

// ---------------------------------------------------------------------------
// Kernel 0: W -> bf16 hi/lo frag-major  +  zero-init pamax1/rmax1/done_ct.
// ---------------------------------------------------------------------------
__global__ __launch_bounds__(256) void wfrag_kernel(
    const float* __restrict__ Wq, const float* __restrict__ Wk,
    unsigned short* __restrict__ Whf, unsigned short* __restrict__ Wlf,
    unsigned* __restrict__ initp)
{
    for (unsigned g = blockIdx.x * 256 + threadIdx.x; g < INITN; g += gridDim.x * 256)
        initp[g] = 0u;

    const int idx = blockIdx.x * 256 + threadIdx.x;
    if (idx >= WCH) return;
    const int lane = idx & 63, rest = idx >> 6;
    const int ks = rest % 10, r2 = rest / 10;
    const int nt = r2 & 1, r3 = r2 >> 1;
    const int jtg = r3 % 12, z = r3 / 12;
    const int n16 = lane & 15, quad = lane >> 4;
    const int j = jtg * 32 + nt * 16 + n16;
    const int head = j >> 6, dd = j & 63;
    const float* W = z ? Wk : Wq;

    bs8 vh, vl;
#pragma unroll
    for (int e = 0; e < 8; ++e) {
        int k = ks * 32 + quad * 8 + e;
        float v = (dd < DH && k < 300) ? W[(head * DH + dd) * 300 + (k < 300 ? k : 0)] : 0.f;
        unsigned short h = f2bf(v);
        vh[e] = (short)h;
        vl[e] = (short)f2bf(v - bf2f(h));
    }
    *(bs8*)(Whf + (size_t)idx * 8) = vh;
    *(bs8*)(Wlf + (size_t)idx * 8) = vl;
}

// ---------------------------------------------------------------------------
// Kernel 1: projection, split-bf16 MFMA (XhWh + XlWh + XhWl), A read ONCE.
// ---------------------------------------------------------------------------
__global__ __launch_bounds__(256, 1) void proj_mfma_kernel(
    const float* __restrict__ Xq, const float* __restrict__ Xk,
    const unsigned short* __restrict__ Whf, const unsigned short* __restrict__ Wlf,
    float* __restrict__ Qt, float* __restrict__ Kt,
    unsigned short* __restrict__ Qb, unsigned short* __restrict__ Kb)
{
    __shared__ unsigned short Bsh[2][2560 * 8];
    __shared__ unsigned short Tr[4][32][40];

    const int z  = blockIdx.z;
    const int jg = blockIdx.y;
    const int m0 = blockIdx.x * 128;
    const float* X = z ? Xk : Xq;
    float*          Ytf = z ? Kt : Qt;
    unsigned short* Ytb = z ? Kb : Qb;

    const int tid = threadIdx.x;
    const int wave = tid >> 6, lane = tid & 63;
    const int m16 = lane & 15, quad = lane >> 4;
    const int n = m0 >> 12, t0 = m0 & (T - 1);

    bs8 Ah[2][10], Al[2][10];
#pragma unroll
    for (int mt = 0; mt < 2; ++mt) {
        const float* rowp = X + (size_t)(m0 + wave * 32 + mt * 16 + m16) * 300;
#pragma unroll
        for (int ks = 0; ks < 10; ++ks) {
            float f[8];
            if (ks < 9) {
                float4 a = *(const float4*)(rowp + ks * 32 + quad * 8);
                float4 c = *(const float4*)(rowp + ks * 32 + quad * 8 + 4);
                f[0] = a.x; f[1] = a.y; f[2] = a.z; f[3] = a.w;
                f[4] = c.x; f[5] = c.y; f[6] = c.z; f[7] = c.w;
            } else {
#pragma unroll
                for (int e = 0; e < 8; ++e) {
                    int k = 288 + quad * 8 + e;
                    f[e] = (k < 300) ? rowp[k < 300 ? k : 0] : 0.f;
                }
            }
#pragma unroll
            for (int e = 0; e < 8; ++e) {
                unsigned short h = f2bf(f[e]);
                Ah[mt][ks][e] = (short)h;
                Al[mt][ks][e] = (short)f2bf(f[e] - bf2f(h));
            }
        }
    }

    bs8 rh[5], rl[5];
    {
        size_t cb = (size_t)(z * 12 + jg * 6) * 1280;
#pragma unroll
        for (int i = 0; i < 5; ++i) {
            int c = i * 256 + tid;
            rh[i] = *(const bs8*)(Whf + (cb + c) * 8);
            rl[i] = *(const bs8*)(Wlf + (cb + c) * 8);
        }
#pragma unroll
        for (int i = 0; i < 5; ++i) {
            int c = i * 256 + tid;
            *(bs8*)&Bsh[0][c * 8]          = rh[i];
            *(bs8*)&Bsh[0][(1280 + c) * 8] = rl[i];
        }
    }

    f4 acc[2][2] = {{{0.f,0.f,0.f,0.f},{0.f,0.f,0.f,0.f}},
                    {{0.f,0.f,0.f,0.f},{0.f,0.f,0.f,0.f}}};

    for (int jt = 0; jt < 6; ++jt) {
        __syncthreads();

        if (jt < 5) {
            size_t cb = (size_t)(z * 12 + jg * 6 + jt + 1) * 1280;
#pragma unroll
            for (int i = 0; i < 5; ++i) {
                int c = i * 256 + tid;
                rh[i] = *(const bs8*)(Whf + (cb + c) * 8);
                rl[i] = *(const bs8*)(Wlf + (cb + c) * 8);
            }
        }

        const unsigned short* Bbuf = Bsh[jt & 1];
#pragma unroll
        for (int ks = 0; ks < 10; ++ks) {
#pragma unroll
            for (int nt = 0; nt < 2; ++nt) {
                bs8 bh = *(const bs8*)&Bbuf[((nt * 10 + ks) * 64 + lane) * 8];
                bs8 bl = *(const bs8*)&Bbuf[((1280 + (nt * 10 + ks) * 64) + lane) * 8];
#pragma unroll
                for (int mt = 0; mt < 2; ++mt) {
                    acc[mt][nt] = __builtin_amdgcn_mfma_f32_16x16x32_bf16(Ah[mt][ks], bh, acc[mt][nt], 0, 0, 0);
                    acc[mt][nt] = __builtin_amdgcn_mfma_f32_16x16x32_bf16(Al[mt][ks], bh, acc[mt][nt], 0, 0, 0);
                    acc[mt][nt] = __builtin_amdgcn_mfma_f32_16x16x32_bf16(Ah[mt][ks], bl, acc[mt][nt], 0, 0, 0);
                }
            }
        }

        const int jtg  = jg * 6 + jt;
        const int head = jtg >> 1, d0 = (jtg & 1) * 32;
        const int b    = head * NB + n;

#pragma unroll
        for (int nt = 0; nt < 2; ++nt) {
            const int dd = d0 + nt * 16 + m16;
            if (dd < DH) {
                float* base = Ytf + ((size_t)b * DH + dd) * T + t0 + wave * 32;
#pragma unroll
                for (int mt = 0; mt < 2; ++mt)
                    *(float4*)(base + mt * 16 + quad * 4) =
                        make_float4(acc[mt][nt][0], acc[mt][nt][1], acc[mt][nt][2], acc[mt][nt][3]);
            }
        }

#pragma unroll
        for (int mt = 0; mt < 2; ++mt)
#pragma unroll
            for (int nt = 0; nt < 2; ++nt)
#pragma unroll
                for (int r = 0; r < 4; ++r)
                    Tr[wave][mt * 16 + quad * 4 + r][nt * 16 + m16] = f2bf(acc[mt][nt][r]);
        {
            const int rr = lane >> 1, p = lane & 1;
            unsigned short* dst = Ytb + ((size_t)b * T + t0 + wave * 32 + rr) * 64 + d0 + p * 16;
            *(bs8*)dst       = *(const bs8*)&Tr[wave][rr][p * 16];
            *(bs8*)(dst + 8) = *(const bs8*)&Tr[wave][rr][p * 16 + 8];
        }

#pragma unroll
        for (int mt = 0; mt < 2; ++mt)
#pragma unroll
            for (int nt = 0; nt < 2; ++nt)
                acc[mt][nt] = (f4){0.f, 0.f, 0.f, 0.f};

        __syncthreads();
        if (jt < 5) {
#pragma unroll
            for (int i = 0; i < 5; ++i) {
                int c = i * 256 + tid;
                *(bs8*)&Bsh[(jt + 1) & 1][c * 8]          = rh[i];
                *(bs8*)&Bsh[(jt + 1) & 1][(1280 + c) * 8] = rl[i];
            }
        }
    }
}

// ---------------------------------------------------------------------------
// Kernel 2: bf16 MFMA scores + column max -> atomicMax(fkey) into pamax1.
// ---------------------------------------------------------------------------
__global__ __launch_bounds__(256) void score_mfma_kernel(
    const unsigned short* __restrict__ Qb, const unsigned short* __restrict__ Kb,
    unsigned* __restrict__ pamax1)
{
    __shared__ unsigned short Qlds[2][1024 * 8];   // 2 x 16 KB, XOR-swizzled

    const int kb   = blockIdx.x;
    const int b    = blockIdx.y;
    const int qc   = blockIdx.z;
    const int tid  = threadIdx.x;
    const int wave = tid >> 6, lane = tid & 63;
    const int m16  = lane & 15, quad = lane >> 4;

    const int k0 = kb * 256 + wave * 64;

    bs8 Bf[4][2];
#pragma unroll
    for (int kt = 0; kt < 4; ++kt)
#pragma unroll
        for (int h = 0; h < 2; ++h)
            Bf[kt][h] = *(const bs8*)(Kb + ((size_t)(b * T + k0 + kt * 16 + m16)) * 64
                                         + quad * 8 + h * 32);

    float cmax[4];
#pragma unroll
    for (int kt = 0; kt < 4; ++kt) cmax[kt] = -INFINITY;

    const int r_ = tid >> 3, c2_ = tid & 7;
    bs8 pre[4];
#pragma unroll
    for (int i = 0; i < 4; ++i)
        pre[i] = *(const bs8*)(Qb + ((size_t)(b * T + qc * 1024 + i * 32 + r_)) * 64 + c2_ * 8);
#pragma unroll
    for (int i = 0; i < 4; ++i) {
        int row = i * 32 + r_;
        *(bs8*)&Qlds[0][(row * 8 + (c2_ ^ (row & 7))) * 8] = pre[i];
    }

    for (int it = 0; it < 8; ++it) {
        __syncthreads();
        if (it < 7) {
            const int q0 = qc * 1024 + (it + 1) * 128;
#pragma unroll
            for (int i = 0; i < 4; ++i)
                pre[i] = *(const bs8*)(Qb + ((size_t)(b * T + q0 + i * 32 + r_)) * 64 + c2_ * 8);
        }

        const unsigned short* Ql = Qlds[it & 1];
#pragma unroll
        for (int mt = 0; mt < 8; ++mt) {
            const int row = mt * 16 + m16;
            bs8 A0 = *(const bs8*)&Ql[(row * 8 + (quad ^ (row & 7))) * 8];
            bs8 A1 = *(const bs8*)&Ql[(row * 8 + ((quad + 4) ^ (row & 7))) * 8];
#pragma unroll
            for (int kt = 0; kt < 4; ++kt) {
                f4 acc = {0.f, 0.f, 0.f, 0.f};
                acc = __builtin_amdgcn_mfma_f32_16x16x32_bf16(A0, Bf[kt][0], acc, 0, 0, 0);
                acc = __builtin_amdgcn_mfma_f32_16x16x32_bf16(A1, Bf[kt][1], acc, 0, 0, 0);
                cmax[kt] = fmaxf(cmax[kt],
                                 fmaxf(fmaxf(acc[0], acc[1]), fmaxf(acc[2], acc[3])));
            }
        }
        __syncthreads();
        if (it < 7) {
#pragma unroll
            for (int i = 0; i < 4; ++i) {
                int row = i * 32 + r_;
                *(bs8*)&Qlds[(it + 1) & 1][(row * 8 + (c2_ ^ (row & 7))) * 8] = pre[i];
            }
        }
    }

#pragma unroll
    for (int kt = 0; kt < 4; ++kt) {
        float v = cmax[kt];
        v = fmaxf(v, __shfl_xor(v, 16));
        v = fmaxf(v, __shfl_xor(v, 32));
        if (lane < 16)
            atomicMax(&pamax1[(size_t)b * T + k0 + kt * 16 + lane], fkey(v));
    }
}

// ---------------------------------------------------------------------------
// Kernel 3: per batch (12 blocks), radix-select top-NCAND candidate SET,
// rank-sorted by index -> cand[b][48]; also gathers candKT[b][50][48].
// ---------------------------------------------------------------------------
__global__ __launch_bounds__(256) void cand_kernel(
    const unsigned* __restrict__ pamax1, const float* __restrict__ Kt,
    int* __restrict__ cand, float* __restrict__ candKT)
{
    __shared__ unsigned vals[T];
    __shared__ int      hist[NBINS];
    __shared__ int      part[256];
    __shared__ int      bidx[BMAX];
    __shared__ unsigned bval[BMAX];
    __shared__ int      candtmp[NCAND];
    __shared__ int      cand_sorted[NCAND];
    __shared__ int      sh_B, sh_nout, sh_nb;

    const int b = blockIdx.x, tid = threadIdx.x;

    for (int i = tid; i < NBINS; i += 256) hist[i] = 0;
    if (tid == 0) { sh_nout = 0; sh_nb = 0; }
    __syncthreads();

    for (int i = tid; i < T; i += 256) {
        unsigned k = pamax1[(size_t)b * T + i];
        vals[i] = k;
        atomicAdd(&hist[k >> 20], 1);
    }
    __syncthreads();
    {
        int s = 0;
#pragma unroll
        for (int k = 0; k < 16; ++k) s += hist[tid * 16 + k];
        part[tid] = s;
        __syncthreads();
        for (int off = 1; off < 256; off <<= 1) {
            int v = (tid + off < 256) ? part[tid + off] : 0;
            __syncthreads();
            part[tid] += v;
            __syncthreads();
        }
        int run = (tid < 255) ? part[tid + 1] : 0;
        for (int k = 15; k >= 0; --k) {
            int bin = tid * 16 + k;
            int c = hist[bin];
            if (run < NCAND && run + c >= NCAND) sh_B = bin;
            run += c;
        }
    }
    __syncthreads();
    const int B = sh_B;

    for (int i = tid; i < T; i += 256) {
        int kb2 = (int)(vals[i] >> 20);
        if (kb2 > B) {
            int p = atomicAdd(&sh_nout, 1);
            candtmp[p] = i;
        } else if (kb2 == B) {
            int p = atomicAdd(&sh_nb, 1);
            if (p < BMAX) { bidx[p] = i; bval[p] = vals[i]; }
        }
    }
    __syncthreads();
    const int c1 = sh_nout, need = NCAND - c1;
    const int nb = (sh_nb < BMAX) ? sh_nb : BMAX;
    if (tid < 64) {
        for (int l = 0; l < need; ++l) {
            unsigned mv = 0; int mp = -1, mt = 0x7fffffff;
            for (int j = tid; j < nb; j += 64) {
                unsigned v = bval[j]; int t = bidx[j];
                if (v > mv || (v == mv && t < mt)) { mv = v; mp = j; mt = t; }
            }
#pragma unroll
            for (int off = 32; off > 0; off >>= 1) {
                unsigned v2 = (unsigned)__shfl_xor((int)mv, off);
                int p2 = __shfl_xor(mp, off);
                int t2 = __shfl_xor(mt, off);
                if (v2 > mv || (v2 == mv && t2 < mt)) { mv = v2; mp = p2; mt = t2; }
            }
            if (tid == 0) candtmp[c1 + l] = (mp >= 0) ? bidx[mp] : 0;
            if (mp >= 0 && tid == (mp & 63)) bval[mp] = 0;
        }
    }
    __syncthreads();

    // rank-sort by index -> deterministic j-order
    if (tid < NCAND) {
        int myt = candtmp[tid], rank = 0;
        for (int j = 0; j < NCAND; ++j) rank += (candtmp[j] < myt);
        cand_sorted[rank] = myt;
    }
    __syncthreads();
    if (tid < NCAND) cand[b * NCAND + tid] = cand_sorted[tid];

    // gather candidate K columns: candKT[b][d][j]
    for (int i = tid; i < DH * NCAND; i += 256) {
        int d = i / NCAND, j = i - d * NCAND;
        candKT[(size_t)b * (DH * NCAND) + i] =
            Kt[((size_t)b * DH + d) * T + cand_sorted[j]];
    }
}

// ---------------------------------------------------------------------------
// Kernel 4: fused rescore + finale. grid (12 b, 64 qch of 64 queries).
// All 4 waves share the block's 64 queries (q = lane); wave w owns candidates
// [w*12, w*12+12). d-loop chunked 5x10 (#pragma nounroll) to cap the register
// live range (<~100 VGPR; round-10's full unroll hit 256 + scratch spill).
// ---------------------------------------------------------------------------
__global__ __launch_bounds__(256) void rescore_final_kernel(
    const int* __restrict__ cand, const float* __restrict__ candKT,
    const float* __restrict__ Qt, const float* __restrict__ Kt,
    unsigned* __restrict__ rmax1, unsigned* __restrict__ done_ct,
    float* __restrict__ out)
{
    __shared__ float KcT[DH][NCAND];   // [50][48], row = 192 B (16B-aligned)
    __shared__ int   cand_s[NCAND];
    __shared__ int   sh_pos;
    __shared__ float selval[KTOP];
    __shared__ int   selidx[KTOP];
    __shared__ float probs[KTOP];

    const int b = blockIdx.x, qch = blockIdx.y;
    const int tid = threadIdx.x, lane = tid & 63, wv = tid >> 6;

    if (tid < NCAND) cand_s[tid] = cand[b * NCAND + tid];
    for (int i = tid; i < DH * NCAND / 4; i += 256)
        ((float4*)&KcT[0][0])[i] = ((const float4*)(candKT + (size_t)b * (DH * NCAND)))[i];
    __syncthreads();

    const int q  = qch * 64 + lane;
    const int j0 = wv * 12;
    float cm[12];
#pragma unroll
    for (int j = 0; j < 12; ++j) cm[j] = 0.f;

#pragma nounroll
    for (int dc = 0; dc < 5; ++dc) {
        float qv[10];
#pragma unroll
        for (int e = 0; e < 10; ++e)
            qv[e] = Qt[((size_t)b * DH + dc * 10 + e) * T + q];
#pragma unroll
        for (int e = 0; e < 10; ++e) {
            const int d = dc * 10 + e;
            float4 k0 = *(const float4*)&KcT[d][j0];       // wave-broadcast reads
            float4 k1 = *(const float4*)&KcT[d][j0 + 4];
            float4 k2 = *(const float4*)&KcT[d][j0 + 8];
            float x = qv[e];
            cm[0]  = fmaf(x, k0.x, cm[0]);
            cm[1]  = fmaf(x, k0.y, cm[1]);
            cm[2]  = fmaf(x, k0.z, cm[2]);
            cm[3]  = fmaf(x, k0.w, cm[3]);
            cm[4]  = fmaf(x, k1.x, cm[4]);
            cm[5]  = fmaf(x, k1.y, cm[5]);
            cm[6]  = fmaf(x, k1.z, cm[6]);
            cm[7]  = fmaf(x, k1.w, cm[7]);
            cm[8]  = fmaf(x, k2.x, cm[8]);
            cm[9]  = fmaf(x, k2.y, cm[9]);
            cm[10] = fmaf(x, k2.z, cm[10]);
            cm[11] = fmaf(x, k2.w, cm[11]);
        }
    }

#pragma unroll
    for (int j = 0; j < 12; ++j) {
        float v = cm[j];
#pragma unroll
        for (int off = 32; off > 0; off >>= 1)
            v = fmaxf(v, __shfl_xor(v, off));
        if (lane == 0)
            atomicMax(&rmax1[b * NCAND + j0 + j], fkey(v));
    }
    __syncthreads();
    if (tid == 0) {
        __threadfence();
        sh_pos = atomicAdd(&done_ct[b], 1u);
    }
    __syncthreads();
    if (sh_pos != RQC2 - 1) return;   // uniform per block

    // --- last block for this b: exact finale ---
    if (tid < 64) {
        float v = -INFINITY; int idx = 0x7fffffff;
        if (lane < NCAND) {
            unsigned u = atomicMax(&rmax1[b * NCAND + lane], 0u);  // coherent read
            v = fkey_inv(u) * 0.14142135623730951f;                // 1/sqrt(50)
            idx = cand_s[lane];
        }
        for (int l = 0; l < KTOP; ++l) {
            float mv = v; int mi = idx;
#pragma unroll
            for (int off = 32; off > 0; off >>= 1) {
                float v2 = __shfl_xor(mv, off);
                int   i2 = __shfl_xor(mi, off);
                if (v2 > mv || (v2 == mv && i2 < mi)) { mv = v2; mi = i2; }
            }
            if (idx == mi) v = -INFINITY;   // cand indices distinct
            if (lane == 0) { selval[l] = mv; selidx[l] = mi; }
        }
    }
    __syncthreads();
    if (tid == 0) {
        float m = selval[0];
        float s = 0.f;
        for (int l = 0; l < KTOP; ++l) { float e = expf(selval[l] - m); probs[l] = e; s += e; }
        float inv = 1.f / s;
        for (int l = 0; l < KTOP; ++l) probs[l] *= inv;
    }
    __syncthreads();
    if (tid < DH) {
        float acc = 0.f;
#pragma unroll
        for (int l = 0; l < KTOP; ++l)
            acc += probs[l] * Kt[((size_t)b * DH + tid) * T + selidx[l]];
        int head = b / NB, n = b % NB;
        out[n * Dm + head * DH + tid] = acc;
    }
}

// ---------------------------------------------------------------------------
extern "C" void kernel_launch(void* const* d_in, const int* in_sizes, int n_in,
                              void* d_out, int out_size, void* d_ws, size_t ws_size,
                              hipStream_t stream) {
    const float* querys = (const float*)d_in[0];
    const float* keys   = (const float*)d_in[1];
    const float* Wq     = (const float*)d_in[3];
    const float* Wk     = (const float*)d_in[4];

    float* out = (float*)d_out;
    float* ws  = (float*)d_ws;

    float* Qt = ws;                                       // 12*50*4096 f
    float* Kt = Qt + (size_t)NBATCH * DH * T;             // 12*50*4096 f
    unsigned* pamax1  = (unsigned*)(Kt + (size_t)NBATCH * DH * T);  // 12*4096 u
    unsigned* rmax1   = pamax1 + (size_t)NBATCH * T;      // 12*48 u
    unsigned* done_ct = rmax1 + (size_t)NBATCH * NCAND;   // 12 u
    int* cand = (int*)(done_ct + NBATCH);                 // 12*48 i
    float* candKT = (float*)(cand + NBATCH * NCAND);      // 12*50*48 f
    unsigned short* Qb = (unsigned short*)(candKT + (size_t)NBATCH * DH * NCAND + 4);
    Qb = (unsigned short*)(((uintptr_t)Qb + 15) & ~(uintptr_t)15);
    unsigned short* Kb  = Qb  + (size_t)NBATCH * T * 64;  // 12*4096*64 ush
    unsigned short* Whf = Kb  + (size_t)NBATCH * T * 64;  // WCH*8 ush
    unsigned short* Wlf = Whf + (size_t)WCH * 8;
    // total ~33.6 MB

    wfrag_kernel      <<<(WCH + 255) / 256, 256, 0, stream>>>(Wq, Wk, Whf, Wlf, pamax1);
    proj_mfma_kernel  <<<dim3(64, 2, 2), 256, 0, stream>>>(querys, keys, Whf, Wlf, Qt, Kt, Qb, Kb);
    score_mfma_kernel <<<dim3(16, NBATCH, QC), 256, 0, stream>>>(Qb, Kb, pamax1);
    cand_kernel       <<<NBATCH, 256, 0, stream>>>(pamax1, Kt, cand, candKT);
    rescore_final_kernel<<<dim3(NBATCH, RQC2), 256, 0, stream>>>(cand, candKT, Qt, Kt, rmax1, done_ct, out);
}

// Round 12
// 202.991 us; speedup vs baseline: 1.3039x; 1.0525x over previous
//
#include <hip/hip_runtime.h>
#include <hip/hip_bf16.h>
#include <math.h>

// Problem constants (reference: D=300, TOPK=20, setup N=2,T=4096,h=6)
#define T      4096
#define Dm     300
#define NH     6
#define DH     50
#define NB     2
#define NBATCH 12   // NH*NB
#define KTOP   20
#define NCAND  48   // rank20->48 margin ~0.28 >> bf16 score err ~6e-3
#define QC     4    // score kernel q-chunks (grid.z), 1024 queries each
#define RQC2   64   // rescore q-chunks (64 queries each, one per lane)
#define NBINS  4096 // radix-select histogram bins (top 12 key bits)
#define BMAX   1024 // boundary-bin list cap
#define WCH    30720        // W frag chunks: 2z*12jt*2nt*10ks*64lane
#define INITN  (NBATCH * T)   // pamax1 only (rmaxq is fully overwritten)

typedef short  bs8  __attribute__((ext_vector_type(8)));   // 8 bf16 = 4 VGPRs
typedef float  f4   __attribute__((ext_vector_type(4)));

static __device__ __forceinline__ unsigned short f2bf(float f) {
    union { float f; unsigned u; } x{f};
    unsigned r = x.u + 0x7fffu + ((x.u >> 16) & 1u);   // RNE
    return (unsigned short)(r >> 16);
}
static __device__ __forceinline__ float bf2f(unsigned short h) {
    union { unsigned u; float f; } x;
    x.u = ((unsigned)h) << 16;
    return x.f;
}
// order-preserving float -> uint key (a>b <=> fkey(a)>fkey(b))
static __device__ __forceinline__ unsigned fkey(float f) {
    unsigned u = __float_as_uint(f);
    return (u & 0x80000000u) ? ~u : (u | 0x80000000u);
}

// ---------------------------------------------------------------------------
// Kernel 0: W -> bf16 hi/lo frag-major  +  zero-init pamax1.
// ---------------------------------------------------------------------------
__global__ __launch_bounds__(256) void wfrag_kernel(
    const float* __restrict__ Wq, const float* __restrict__ Wk,
    unsigned short* __restrict__ Whf, unsigned short* __restrict__ Wlf,
    unsigned* __restrict__ initp)
{
    for (unsigned g = blockIdx.x * 256 + threadIdx.x; g < INITN; g += gridDim.x * 256)
        initp[g] = 0u;

    const int idx = blockIdx.x * 256 + threadIdx.x;
    if (idx >= WCH) return;
    const int lane = idx & 63, rest = idx >> 6;
    const int ks = rest % 10, r2 = rest / 10;
    const int nt = r2 & 1, r3 = r2 >> 1;
    const int jtg = r3 % 12, z = r3 / 12;
    const int n16 = lane & 15, quad = lane >> 4;
    const int j = jtg * 32 + nt * 16 + n16;
    const int head = j >> 6, dd = j & 63;
    const float* W = z ? Wk : Wq;

    bs8 vh, vl;
#pragma unroll
    for (int e = 0; e < 8; ++e) {
        int k = ks * 32 + quad * 8 + e;
        float v = (dd < DH && k < 300) ? W[(head * DH + dd) * 300 + (k < 300 ? k : 0)] : 0.f;
        unsigned short h = f2bf(v);
        vh[e] = (short)h;
        vl[e] = (short)f2bf(v - bf2f(h));
    }
    *(bs8*)(Whf + (size_t)idx * 8) = vh;
    *(bs8*)(Wlf + (size_t)idx * 8) = vl;
}

// ---------------------------------------------------------------------------
// Kernel 1: projection, split-bf16 MFMA (XhWh + XlWh + XhWl), A read ONCE.
// ---------------------------------------------------------------------------
__global__ __launch_bounds__(256, 1) void proj_mfma_kernel(
    const float* __restrict__ Xq, const float* __restrict__ Xk,
    const unsigned short* __restrict__ Whf, const unsigned short* __restrict__ Wlf,
    float* __restrict__ Qt, float* __restrict__ Kt,
    unsigned short* __restrict__ Qb, unsigned short* __restrict__ Kb)
{
    __shared__ unsigned short Bsh[2][2560 * 8];
    __shared__ unsigned short Tr[4][32][40];

    const int z  = blockIdx.z;
    const int jg = blockIdx.y;
    const int m0 = blockIdx.x * 128;
    const float* X = z ? Xk : Xq;
    float*          Ytf = z ? Kt : Qt;
    unsigned short* Ytb = z ? Kb : Qb;

    const int tid = threadIdx.x;
    const int wave = tid >> 6, lane = tid & 63;
    const int m16 = lane & 15, quad = lane >> 4;
    const int n = m0 >> 12, t0 = m0 & (T - 1);

    bs8 Ah[2][10], Al[2][10];
#pragma unroll
    for (int mt = 0; mt < 2; ++mt) {
        const float* rowp = X + (size_t)(m0 + wave * 32 + mt * 16 + m16) * 300;
#pragma unroll
        for (int ks = 0; ks < 10; ++ks) {
            float f[8];
            if (ks < 9) {
                float4 a = *(const float4*)(rowp + ks * 32 + quad * 8);
                float4 c = *(const float4*)(rowp + ks * 32 + quad * 8 + 4);
                f[0] = a.x; f[1] = a.y; f[2] = a.z; f[3] = a.w;
                f[4] = c.x; f[5] = c.y; f[6] = c.z; f[7] = c.w;
            } else {
#pragma unroll
                for (int e = 0; e < 8; ++e) {
                    int k = 288 + quad * 8 + e;
                    f[e] = (k < 300) ? rowp[k < 300 ? k : 0] : 0.f;
                }
            }
#pragma unroll
            for (int e = 0; e < 8; ++e) {
                unsigned short h = f2bf(f[e]);
                Ah[mt][ks][e] = (short)h;
                Al[mt][ks][e] = (short)f2bf(f[e] - bf2f(h));
            }
        }
    }

    bs8 rh[5], rl[5];
    {
        size_t cb = (size_t)(z * 12 + jg * 6) * 1280;
#pragma unroll
        for (int i = 0; i < 5; ++i) {
            int c = i * 256 + tid;
            rh[i] = *(const bs8*)(Whf + (cb + c) * 8);
            rl[i] = *(const bs8*)(Wlf + (cb + c) * 8);
        }
#pragma unroll
        for (int i = 0; i < 5; ++i) {
            int c = i * 256 + tid;
            *(bs8*)&Bsh[0][c * 8]          = rh[i];
            *(bs8*)&Bsh[0][(1280 + c) * 8] = rl[i];
        }
    }

    f4 acc[2][2] = {{{0.f,0.f,0.f,0.f},{0.f,0.f,0.f,0.f}},
                    {{0.f,0.f,0.f,0.f},{0.f,0.f,0.f,0.f}}};

    for (int jt = 0; jt < 6; ++jt) {
        __syncthreads();

        if (jt < 5) {
            size_t cb = (size_t)(z * 12 + jg * 6 + jt + 1) * 1280;
#pragma unroll
            for (int i = 0; i < 5; ++i) {
                int c = i * 256 + tid;
                rh[i] = *(const bs8*)(Whf + (cb + c) * 8);
                rl[i] = *(const bs8*)(Wlf + (cb + c) * 8);
            }
        }

        const unsigned short* Bbuf = Bsh[jt & 1];
#pragma unroll
        for (int ks = 0; ks < 10; ++ks) {
#pragma unroll
            for (int nt = 0; nt < 2; ++nt) {
                bs8 bh = *(const bs8*)&Bbuf[((nt * 10 + ks) * 64 + lane) * 8];
                bs8 bl = *(const bs8*)&Bbuf[((1280 + (nt * 10 + ks) * 64) + lane) * 8];
#pragma unroll
                for (int mt = 0; mt < 2; ++mt) {
                    acc[mt][nt] = __builtin_amdgcn_mfma_f32_16x16x32_bf16(Ah[mt][ks], bh, acc[mt][nt], 0, 0, 0);
                    acc[mt][nt] = __builtin_amdgcn_mfma_f32_16x16x32_bf16(Al[mt][ks], bh, acc[mt][nt], 0, 0, 0);
                    acc[mt][nt] = __builtin_amdgcn_mfma_f32_16x16x32_bf16(Ah[mt][ks], bl, acc[mt][nt], 0, 0, 0);
                }
            }
        }

        const int jtg  = jg * 6 + jt;
        const int head = jtg >> 1, d0 = (jtg & 1) * 32;
        const int b    = head * NB + n;

#pragma unroll
        for (int nt = 0; nt < 2; ++nt) {
            const int dd = d0 + nt * 16 + m16;
            if (dd < DH) {
                float* base = Ytf + ((size_t)b * DH + dd) * T + t0 + wave * 32;
#pragma unroll
                for (int mt = 0; mt < 2; ++mt)
                    *(float4*)(base + mt * 16 + quad * 4) =
                        make_float4(acc[mt][nt][0], acc[mt][nt][1], acc[mt][nt][2], acc[mt][nt][3]);
            }
        }

#pragma unroll
        for (int mt = 0; mt < 2; ++mt)
#pragma unroll
            for (int nt = 0; nt < 2; ++nt)
#pragma unroll
                for (int r = 0; r < 4; ++r)
                    Tr[wave][mt * 16 + quad * 4 + r][nt * 16 + m16] = f2bf(acc[mt][nt][r]);
        {
            const int rr = lane >> 1, p = lane & 1;
            unsigned short* dst = Ytb + ((size_t)b * T + t0 + wave * 32 + rr) * 64 + d0 + p * 16;
            *(bs8*)dst       = *(const bs8*)&Tr[wave][rr][p * 16];
            *(bs8*)(dst + 8) = *(const bs8*)&Tr[wave][rr][p * 16 + 8];
        }

#pragma unroll
        for (int mt = 0; mt < 2; ++mt)
#pragma unroll
            for (int nt = 0; nt < 2; ++nt)
                acc[mt][nt] = (f4){0.f, 0.f, 0.f, 0.f};

        __syncthreads();
        if (jt < 5) {
#pragma unroll
            for (int i = 0; i < 5; ++i) {
                int c = i * 256 + tid;
                *(bs8*)&Bsh[(jt + 1) & 1][c * 8]          = rh[i];
                *(bs8*)&Bsh[(jt + 1) & 1][(1280 + c) * 8] = rl[i];
            }
        }
    }
}

// ---------------------------------------------------------------------------
// Kernel 2: bf16 MFMA scores + column max -> atomicMax(fkey) into pamax1.
// ---------------------------------------------------------------------------
__global__ __launch_bounds__(256) void score_mfma_kernel(
    const unsigned short* __restrict__ Qb, const unsigned short* __restrict__ Kb,
    unsigned* __restrict__ pamax1)
{
    __shared__ unsigned short Qlds[2][1024 * 8];   // 2 x 16 KB, XOR-swizzled

    const int kb   = blockIdx.x;
    const int b    = blockIdx.y;
    const int qc   = blockIdx.z;
    const int tid  = threadIdx.x;
    const int wave = tid >> 6, lane = tid & 63;
    const int m16  = lane & 15, quad = lane >> 4;

    const int k0 = kb * 256 + wave * 64;

    bs8 Bf[4][2];
#pragma unroll
    for (int kt = 0; kt < 4; ++kt)
#pragma unroll
        for (int h = 0; h < 2; ++h)
            Bf[kt][h] = *(const bs8*)(Kb + ((size_t)(b * T + k0 + kt * 16 + m16)) * 64
                                         + quad * 8 + h * 32);

    float cmax[4];
#pragma unroll
    for (int kt = 0; kt < 4; ++kt) cmax[kt] = -INFINITY;

    const int r_ = tid >> 3, c2_ = tid & 7;
    bs8 pre[4];
#pragma unroll
    for (int i = 0; i < 4; ++i)
        pre[i] = *(const bs8*)(Qb + ((size_t)(b * T + qc * 1024 + i * 32 + r_)) * 64 + c2_ * 8);
#pragma unroll
    for (int i = 0; i < 4; ++i) {
        int row = i * 32 + r_;
        *(bs8*)&Qlds[0][(row * 8 + (c2_ ^ (row & 7))) * 8] = pre[i];
    }

    for (int it = 0; it < 8; ++it) {
        __syncthreads();
        if (it < 7) {
            const int q0 = qc * 1024 + (it + 1) * 128;
#pragma unroll
            for (int i = 0; i < 4; ++i)
                pre[i] = *(const bs8*)(Qb + ((size_t)(b * T + q0 + i * 32 + r_)) * 64 + c2_ * 8);
        }

        const unsigned short* Ql = Qlds[it & 1];
#pragma unroll
        for (int mt = 0; mt < 8; ++mt) {
            const int row = mt * 16 + m16;
            bs8 A0 = *(const bs8*)&Ql[(row * 8 + (quad ^ (row & 7))) * 8];
            bs8 A1 = *(const bs8*)&Ql[(row * 8 + ((quad + 4) ^ (row & 7))) * 8];
#pragma unroll
            for (int kt = 0; kt < 4; ++kt) {
                f4 acc = {0.f, 0.f, 0.f, 0.f};
                acc = __builtin_amdgcn_mfma_f32_16x16x32_bf16(A0, Bf[kt][0], acc, 0, 0, 0);
                acc = __builtin_amdgcn_mfma_f32_16x16x32_bf16(A1, Bf[kt][1], acc, 0, 0, 0);
                cmax[kt] = fmaxf(cmax[kt],
                                 fmaxf(fmaxf(acc[0], acc[1]), fmaxf(acc[2], acc[3])));
            }
        }
        __syncthreads();
        if (it < 7) {
#pragma unroll
            for (int i = 0; i < 4; ++i) {
                int row = i * 32 + r_;
                *(bs8*)&Qlds[(it + 1) & 1][(row * 8 + (c2_ ^ (row & 7))) * 8] = pre[i];
            }
        }
    }

#pragma unroll
    for (int kt = 0; kt < 4; ++kt) {
        float v = cmax[kt];
        v = fmaxf(v, __shfl_xor(v, 16));
        v = fmaxf(v, __shfl_xor(v, 32));
        if (lane < 16)
            atomicMax(&pamax1[(size_t)b * T + k0 + kt * 16 + lane], fkey(v));
    }
}

// ---------------------------------------------------------------------------
// Kernel 3: per batch (12 blocks), radix-select top-NCAND candidate SET,
// rank-sorted by index -> cand[b][48]; also gathers candKT[b][50][48].
// ---------------------------------------------------------------------------
__global__ __launch_bounds__(256) void cand_kernel(
    const unsigned* __restrict__ pamax1, const float* __restrict__ Kt,
    int* __restrict__ cand, float* __restrict__ candKT)
{
    __shared__ unsigned vals[T];
    __shared__ int      hist[NBINS];
    __shared__ int      part[256];
    __shared__ int      bidx[BMAX];
    __shared__ unsigned bval[BMAX];
    __shared__ int      candtmp[NCAND];
    __shared__ int      cand_sorted[NCAND];
    __shared__ int      sh_B, sh_nout, sh_nb;

    const int b = blockIdx.x, tid = threadIdx.x;

    for (int i = tid; i < NBINS; i += 256) hist[i] = 0;
    if (tid == 0) { sh_nout = 0; sh_nb = 0; }
    __syncthreads();

    for (int i = tid; i < T; i += 256) {
        unsigned k = pamax1[(size_t)b * T + i];
        vals[i] = k;
        atomicAdd(&hist[k >> 20], 1);
    }
    __syncthreads();
    {
        int s = 0;
#pragma unroll
        for (int k = 0; k < 16; ++k) s += hist[tid * 16 + k];
        part[tid] = s;
        __syncthreads();
        for (int off = 1; off < 256; off <<= 1) {
            int v = (tid + off < 256) ? part[tid + off] : 0;
            __syncthreads();
            part[tid] += v;
            __syncthreads();
        }
        int run = (tid < 255) ? part[tid + 1] : 0;
        for (int k = 15; k >= 0; --k) {
            int bin = tid * 16 + k;
            int c = hist[bin];
            if (run < NCAND && run + c >= NCAND) sh_B = bin;
            run += c;
        }
    }
    __syncthreads();
    const int B = sh_B;

    for (int i = tid; i < T; i += 256) {
        int kb2 = (int)(vals[i] >> 20);
        if (kb2 > B) {
            int p = atomicAdd(&sh_nout, 1);
            candtmp[p] = i;
        } else if (kb2 == B) {
            int p = atomicAdd(&sh_nb, 1);
            if (p < BMAX) { bidx[p] = i; bval[p] = vals[i]; }
        }
    }
    __syncthreads();
    const int c1 = sh_nout, need = NCAND - c1;
    const int nb = (sh_nb < BMAX) ? sh_nb : BMAX;
    if (tid < 64) {
        for (int l = 0; l < need; ++l) {
            unsigned mv = 0; int mp = -1, mt = 0x7fffffff;
            for (int j = tid; j < nb; j += 64) {
                unsigned v = bval[j]; int t = bidx[j];
                if (v > mv || (v == mv && t < mt)) { mv = v; mp = j; mt = t; }
            }
#pragma unroll
            for (int off = 32; off > 0; off >>= 1) {
                unsigned v2 = (unsigned)__shfl_xor((int)mv, off);
                int p2 = __shfl_xor(mp, off);
                int t2 = __shfl_xor(mt, off);
                if (v2 > mv || (v2 == mv && t2 < mt)) { mv = v2; mp = p2; mt = t2; }
            }
            if (tid == 0) candtmp[c1 + l] = (mp >= 0) ? bidx[mp] : 0;
            if (mp >= 0 && tid == (mp & 63)) bval[mp] = 0;
        }
    }
    __syncthreads();

    // rank-sort by index -> deterministic j-order
    if (tid < NCAND) {
        int myt = candtmp[tid], rank = 0;
        for (int j = 0; j < NCAND; ++j) rank += (candtmp[j] < myt);
        cand_sorted[rank] = myt;
    }
    __syncthreads();
    if (tid < NCAND) cand[b * NCAND + tid] = cand_sorted[tid];

    // gather candidate K columns: candKT[b][d][j]
    for (int i = tid; i < DH * NCAND; i += 256) {
        int d = i / NCAND, j = i - d * NCAND;
        candKT[(size_t)b * (DH * NCAND) + i] =
            Kt[((size_t)b * DH + d) * T + cand_sorted[j]];
    }
}

// ---------------------------------------------------------------------------
// Kernel 4: rescore only — NO atomics, NO fence, NO counter. grid (12 b, 64
// qch of 64 queries). Wave w owns candidates [w*12, w*12+12); d-loop chunked
// 5x10 (#pragma nounroll) to cap registers. lane0 plain-stores the wave's
// 12 chunk-maxima into rmaxq[b][qch][j]. Kernel boundary orders the finale.
// ---------------------------------------------------------------------------
__global__ __launch_bounds__(256) void rescore_kernel(
    const float* __restrict__ candKT, const float* __restrict__ Qt,
    float* __restrict__ rmaxq)
{
    __shared__ float KcT[DH][NCAND];   // [50][48]

    const int b = blockIdx.x, qch = blockIdx.y;
    const int tid = threadIdx.x, lane = tid & 63, wv = tid >> 6;

    for (int i = tid; i < DH * NCAND / 4; i += 256)
        ((float4*)&KcT[0][0])[i] = ((const float4*)(candKT + (size_t)b * (DH * NCAND)))[i];
    __syncthreads();

    const int q  = qch * 64 + lane;
    const int j0 = wv * 12;
    float cm[12];
#pragma unroll
    for (int j = 0; j < 12; ++j) cm[j] = 0.f;

#pragma nounroll
    for (int dc = 0; dc < 5; ++dc) {
        float qv[10];
#pragma unroll
        for (int e = 0; e < 10; ++e)
            qv[e] = Qt[((size_t)b * DH + dc * 10 + e) * T + q];
#pragma unroll
        for (int e = 0; e < 10; ++e) {
            const int d = dc * 10 + e;
            float4 k0 = *(const float4*)&KcT[d][j0];       // wave-broadcast reads
            float4 k1 = *(const float4*)&KcT[d][j0 + 4];
            float4 k2 = *(const float4*)&KcT[d][j0 + 8];
            float x = qv[e];
            cm[0]  = fmaf(x, k0.x, cm[0]);
            cm[1]  = fmaf(x, k0.y, cm[1]);
            cm[2]  = fmaf(x, k0.z, cm[2]);
            cm[3]  = fmaf(x, k0.w, cm[3]);
            cm[4]  = fmaf(x, k1.x, cm[4]);
            cm[5]  = fmaf(x, k1.y, cm[5]);
            cm[6]  = fmaf(x, k1.z, cm[6]);
            cm[7]  = fmaf(x, k1.w, cm[7]);
            cm[8]  = fmaf(x, k2.x, cm[8]);
            cm[9]  = fmaf(x, k2.y, cm[9]);
            cm[10] = fmaf(x, k2.z, cm[10]);
            cm[11] = fmaf(x, k2.w, cm[11]);
        }
    }

#pragma unroll
    for (int j = 0; j < 12; ++j) {
        float v = cm[j];
#pragma unroll
        for (int off = 32; off > 0; off >>= 1)
            v = fmaxf(v, __shfl_xor(v, off));
        if (lane == 0)
            rmaxq[((size_t)b * RQC2 + qch) * NCAND + j0 + j] = v;
    }
}

// ---------------------------------------------------------------------------
// Kernel 5: finale. 12 blocks x 64 threads: reduce rmaxq over qch, scale,
// exact top-20 (index-asc tie-break), softmax, gather K rows, write output.
// ---------------------------------------------------------------------------
__global__ __launch_bounds__(64) void final2_kernel(
    const float* __restrict__ rmaxq, const int* __restrict__ cand,
    const float* __restrict__ Kt, float* __restrict__ out)
{
    __shared__ float selval[KTOP];
    __shared__ int   selidx[KTOP];
    __shared__ float probs[KTOP];

    const int b = blockIdx.x;
    const int lane = threadIdx.x;

    float v = -INFINITY; int idx = 0x7fffffff;
    if (lane < NCAND) {
        v = rmaxq[(size_t)b * RQC2 * NCAND + lane];
        for (int qc = 1; qc < RQC2; ++qc)
            v = fmaxf(v, rmaxq[((size_t)b * RQC2 + qc) * NCAND + lane]);
        v *= 0.14142135623730951f;   // 1/sqrt(50)
        idx = cand[b * NCAND + lane];
    }

    for (int l = 0; l < KTOP; ++l) {
        float mv = v; int mi = idx;
#pragma unroll
        for (int off = 32; off > 0; off >>= 1) {
            float v2 = __shfl_xor(mv, off);
            int   i2 = __shfl_xor(mi, off);
            if (v2 > mv || (v2 == mv && i2 < mi)) { mv = v2; mi = i2; }
        }
        if (idx == mi) v = -INFINITY;   // cand indices distinct
        if (lane == 0) { selval[l] = mv; selidx[l] = mi; }
    }
    __syncthreads();

    if (lane == 0) {
        float m = selval[0];
        float s = 0.f;
        for (int l = 0; l < KTOP; ++l) { float e = expf(selval[l] - m); probs[l] = e; s += e; }
        float inv = 1.f / s;
        for (int l = 0; l < KTOP; ++l) probs[l] *= inv;
    }
    __syncthreads();

    if (lane < DH) {
        float acc = 0.f;
#pragma unroll
        for (int l = 0; l < KTOP; ++l)
            acc += probs[l] * Kt[((size_t)b * DH + lane) * T + selidx[l]];
        int head = b / NB, n = b % NB;
        out[n * Dm + head * DH + lane] = acc;
    }
}

// ---------------------------------------------------------------------------
extern "C" void kernel_launch(void* const* d_in, const int* in_sizes, int n_in,
                              void* d_out, int out_size, void* d_ws, size_t ws_size,
                              hipStream_t stream) {
    const float* querys = (const float*)d_in[0];
    const float* keys   = (const float*)d_in[1];
    const float* Wq     = (const float*)d_in[3];
    const float* Wk     = (const float*)d_in[4];

    float* out = (float*)d_out;
    float* ws  = (float*)d_ws;

    float* Qt = ws;                                       // 12*50*4096 f
    float* Kt = Qt + (size_t)NBATCH * DH * T;             // 12*50*4096 f
    unsigned* pamax1 = (unsigned*)(Kt + (size_t)NBATCH * DH * T);  // 12*4096 u
    float* rmaxq = (float*)(pamax1 + (size_t)NBATCH * T); // 12*64*48 f
    int* cand = (int*)(rmaxq + (size_t)NBATCH * RQC2 * NCAND);  // 12*48 i
    float* candKT = (float*)(cand + NBATCH * NCAND);      // 12*50*48 f
    unsigned short* Qb = (unsigned short*)(candKT + (size_t)NBATCH * DH * NCAND + 4);
    Qb = (unsigned short*)(((uintptr_t)Qb + 15) & ~(uintptr_t)15);
    unsigned short* Kb  = Qb  + (size_t)NBATCH * T * 64;  // 12*4096*64 ush
    unsigned short* Whf = Kb  + (size_t)NBATCH * T * 64;  // WCH*8 ush
    unsigned short* Wlf = Whf + (size_t)WCH * 8;
    // total ~33.8 MB

    wfrag_kernel      <<<(WCH + 255) / 256, 256, 0, stream>>>(Wq, Wk, Whf, Wlf, pamax1);
    proj_mfma_kernel  <<<dim3(64, 2, 2), 256, 0, stream>>>(querys, keys, Whf, Wlf, Qt, Kt, Qb, Kb);
    score_mfma_kernel <<<dim3(16, NBATCH, QC), 256, 0, stream>>>(Qb, Kb, pamax1);
    cand_kernel       <<<NBATCH, 256, 0, stream>>>(pamax1, Kt, cand, candKT);
    rescore_kernel    <<<dim3(NBATCH, RQC2), 256, 0, stream>>>(candKT, Qt, rmaxq);
    final2_kernel     <<<NBATCH, 64, 0, stream>>>(rmaxq, cand, Kt, out);
}